// Round 19
// baseline (159.978 us; speedup 1.0000x reference)
//
#include <hip/hip_runtime.h>
#include <hip/hip_bf16.h>

typedef short s16x8 __attribute__((ext_vector_type(8)));
typedef float f32x4 __attribute__((ext_vector_type(4)));
typedef unsigned u32x4 __attribute__((ext_vector_type(4)));
typedef unsigned short u16;

#define LOG2E 1.4426950408889634f
#define QSC (0.125f * LOG2E)

typedef __attribute__((address_space(3))) unsigned int lds_u32;
typedef __attribute__((address_space(1))) const unsigned int glb_u32;

static __device__ __forceinline__ void gload16(const void* g, void* l) {
  __builtin_amdgcn_global_load_lds((glb_u32*)g, (lds_u32*)l, 16, 0, 0);
}
static __device__ __forceinline__ u16 bf16u(float f) {
  unsigned u = __builtin_bit_cast(unsigned, f);
  return (u16)((u + 0x7FFFu + ((u >> 16) & 1u)) >> 16);  // RNE
}
static __device__ __forceinline__ unsigned pk(u16 a, u16 b) {
  return (unsigned)a | ((unsigned)b << 16);
}
static __device__ __forceinline__ unsigned cvtpk(float lo, float hi) {
  unsigned d;
  asm("v_cvt_pk_bf16_f32 %0, %1, %2" : "=v"(d) : "v"(lo), "v"(hi));
  return d;
}
static __device__ __forceinline__ unsigned pk2(float a, float b) {
  float2 f; f.x = a; f.y = b;
  __hip_bfloat162 h = __float22bfloat162_rn(f);
  unsigned r;
  __builtin_memcpy(&r, &h, 4);
  return r;
}

// ---------------------------------------------------------------------------
// Prep (merged): blocks 0..1023 binarize weights; blocks 1024..5119 cvt x.
// ---------------------------------------------------------------------------
__global__ __launch_bounds__(256) void k_prep(
    const float* __restrict__ x, u16* __restrict__ xb,
    const float* __restrict__ Wq, const float* __restrict__ Wk,
    const float* __restrict__ Wv, const float* __restrict__ Wp,
    const float* __restrict__ bq, const float* __restrict__ bk,
    const float* __restrict__ bv, const float* __restrict__ bp,
    u16* __restrict__ wbqkv, u16* __restrict__ wbp,
    float* __restrict__ alphaf, float* __restrict__ biasf) {
  if (blockIdx.x >= 1024) {
    int i = ((blockIdx.x - 1024) * 256 + threadIdx.x) * 8;
    float4 a = *reinterpret_cast<const float4*>(x + i);
    float4 b = *reinterpret_cast<const float4*>(x + i + 4);
    uint4 w = { pk2(a.x, a.y), pk2(a.z, a.w), pk2(b.x, b.y), pk2(b.z, b.w) };
    *reinterpret_cast<uint4*>(xb + i) = w;
    return;
  }
  int wave = threadIdx.x >> 6, lane = threadIdx.x & 63;
  int row = blockIdx.x * 4 + wave;
  const float* src; const float* bias; int r;
  if (row < 1024)      { src = Wq; bias = bq; r = row; }
  else if (row < 2048) { src = Wk; bias = bk; r = row - 1024; }
  else if (row < 3072) { src = Wv; bias = bv; r = row - 2048; }
  else                 { src = Wp; bias = bp; r = row - 3072; }
  const float4* s4 = reinterpret_cast<const float4*>(src + r * 1024);
  float4 v[4];
  float asum = 0.f;
#pragma unroll
  for (int i = 0; i < 4; ++i) {
    v[i] = s4[lane * 4 + i];
    asum += fabsf(v[i].x) + fabsf(v[i].y) + fabsf(v[i].z) + fabsf(v[i].w);
  }
#pragma unroll
  for (int m = 32; m >= 1; m >>= 1) asum += __shfl_xor(asum, m, 64);
  float alpha = asum * (1.0f / 1024.0f);

  u16 o[16];
#pragma unroll
  for (int i = 0; i < 4; ++i) {
    const float* f = reinterpret_cast<const float*>(&v[i]);
#pragma unroll
    for (int j = 0; j < 4; ++j) {
      float w = f[j];
      o[i * 4 + j] = (w > 0.f) ? (u16)0x3F80 : ((w < 0.f) ? (u16)0xBF80 : (u16)0);
    }
  }
  u16* dst = (row < 3072 ? wbqkv + row * 1024 : wbp + (row - 3072) * 1024) + lane * 16;
  uint4 w0 = { pk(o[0],o[1]), pk(o[2],o[3]), pk(o[4],o[5]), pk(o[6],o[7]) };
  uint4 w1 = { pk(o[8],o[9]), pk(o[10],o[11]), pk(o[12],o[13]), pk(o[14],o[15]) };
  reinterpret_cast<uint4*>(dst)[0] = w0;
  reinterpret_cast<uint4*>(dst)[1] = w1;
  if (lane == 0) {
    float sc = (row < 1024) ? QSC : 1.0f;
    alphaf[row] = alpha * sc;
    biasf[row]  = bias[r] * sc;
  }
}

// ---------------------------------------------------------------------------
// GEMM-8phase (QKV, 256x256 tile, BK=64, 8 waves, 1 block/CU):
// interleaved wave tiling: wave rows = ah*128 + (wave>>2)*64 + mfl*16,
// cols = bh*128 + (wave&3)*32 + nfl*16 -> quadrant (ah,bh) reads exactly
// A-half ah + B-half bh. Quadrant order (A0B0)(A0B1)(A1B1)(A1B0) staggers
// frees; stage ledger ph0..7 = {t1.A1, t1.B0, t2.A0, t2.B1, t2.A1, t2.B0,
// t3.A0, t3.B1}; vmcnt(4) only at ph3/ph7. Per-fragment k-order = kt asc,
// kk asc == R11 -> bit-identical output. Swizzle pair = R11's proven
// (pre-swizzled source, XOR on read).
// ---------------------------------------------------------------------------
template <int NX, int NWG>
__global__ __launch_bounds__(512, 2) void k_gemm8(
    const u16* __restrict__ A, const u16* __restrict__ Bw,
    const float* __restrict__ alphaf, const float* __restrict__ biasf,
    u16* __restrict__ qbuf, u16* __restrict__ kbuf, u16* __restrict__ vtbuf) {
  __shared__ alignas(128) char smem[131072];  // 2 buf x 4 half-tiles x 16KB
  int tid = threadIdx.x;
  int wave = tid >> 6, lane = tid & 63, g = lane >> 4, ln = lane & 15;
  int wq = wave >> 2;   // m sub-block (0..1)
  int wr = wave & 3;    // n sub-block (0..3)
  int wg = (blockIdx.x & 7) * (NWG / 8) + (blockIdx.x >> 3);
  int m0 = (wg / NX) * 256, n0 = (wg % NX) * 256;

  f32x4 acc[8][4];
#pragma unroll
  for (int i = 0; i < 8; ++i)
#pragma unroll
    for (int j = 0; j < 4; ++j) acc[i][j] = f32x4{0.f, 0.f, 0.f, 0.f};

  const char* Ab = reinterpret_cast<const char*>(A) + m0 * 2048;
  const char* Bb = reinterpret_cast<const char*>(Bw) + n0 * 2048;
  const char* Asrc[2] = { Ab, Ab + 262144 };
  const char* Bsrc[2] = { Bb, Bb + 262144 };

  // stage offsets: round i of a half-tile; LDS linear pos P = i*8192+tid*16
  int soff[2], ldst[2];
#pragma unroll
  for (int i = 0; i < 2; ++i) {
    int r = i * 64 + (tid >> 3);
    int kc = tid & 7;
    soff[i] = r * 2048 + (kc ^ (r & 7)) * 16;
    ldst[i] = i * 8192 + wave * 1024;
  }

#define HT(buf, hid) (smem + (buf) * 65536 + (hid) * 16384)
#define STG(buf, hid, srcb, kt)                                              \
  {                                                                          \
    _Pragma("unroll")                                                        \
    for (int i_ = 0; i_ < 2; ++i_)                                           \
      gload16((srcb) + (kt) * 128 + soff[i_], HT(buf, hid) + ldst[i_]);      \
  }

  s16x8 areg[4][2], breg[2][2];
#define READA(ah, buf)                                                       \
  {                                                                          \
    _Pragma("unroll")                                                        \
    for (int mfl_ = 0; mfl_ < 4; ++mfl_) {                                   \
      int r_ = wq * 64 + mfl_ * 16 + ln;                                     \
      _Pragma("unroll")                                                      \
      for (int kk_ = 0; kk_ < 2; ++kk_)                                      \
        areg[mfl_][kk_] = *reinterpret_cast<const s16x8*>(                   \
            HT(buf, ah) + r_ * 128 + ((kk_ * 64 + g * 16) ^ ((r_ & 7) << 4)));\
    }                                                                        \
  }
#define READB(bh, buf)                                                       \
  {                                                                          \
    _Pragma("unroll")                                                        \
    for (int nfl_ = 0; nfl_ < 2; ++nfl_) {                                   \
      int r_ = wr * 32 + nfl_ * 16 + ln;                                     \
      _Pragma("unroll")                                                      \
      for (int kk_ = 0; kk_ < 2; ++kk_)                                      \
        breg[nfl_][kk_] = *reinterpret_cast<const s16x8*>(                   \
            HT(buf, 2 + (bh)) + r_ * 128 + ((kk_ * 64 + g * 16) ^ ((r_ & 7) << 4)));\
    }                                                                        \
  }
#define MFMA16(ah, bh)                                                       \
  {                                                                          \
    __builtin_amdgcn_s_setprio(1);                                           \
    _Pragma("unroll")                                                        \
    for (int kk_ = 0; kk_ < 2; ++kk_)                                        \
      _Pragma("unroll")                                                      \
      for (int mfl_ = 0; mfl_ < 4; ++mfl_)                                   \
        _Pragma("unroll")                                                    \
        for (int nfl_ = 0; nfl_ < 2; ++nfl_)                                 \
          acc[(ah) * 4 + mfl_][(bh) * 2 + nfl_] =                            \
              __builtin_amdgcn_mfma_f32_16x16x32_bf16(                       \
                  areg[mfl_][kk_], breg[nfl_][kk_],                          \
                  acc[(ah) * 4 + mfl_][(bh) * 2 + nfl_], 0, 0, 0);           \
    __builtin_amdgcn_s_setprio(0);                                           \
  }
#define BAR1()                                                               \
  __builtin_amdgcn_sched_barrier(0);                                         \
  __builtin_amdgcn_s_barrier();                                              \
  asm volatile("s_waitcnt lgkmcnt(0)" ::: "memory");                         \
  __builtin_amdgcn_sched_barrier(0);
#define BAR2()                                                               \
  __builtin_amdgcn_sched_barrier(0);                                         \
  __builtin_amdgcn_s_barrier();
#define VMW(n)                                                               \
  asm volatile("s_waitcnt vmcnt(" #n ")" ::: "memory");                      \
  __builtin_amdgcn_sched_barrier(0);

  // prologue: t0 all 4 halves -> buf0; t1.A0, t1.B1 -> buf1
  STG(0, 0, Asrc[0], 0); STG(0, 1, Asrc[1], 0);
  STG(0, 2, Bsrc[0], 0); STG(0, 3, Bsrc[1], 0);
  STG(1, 0, Asrc[0], 1); STG(1, 3, Bsrc[1], 1);
  VMW(4);
  __builtin_amdgcn_s_barrier();

  for (int it = 0; it < 8; ++it) {
    int t2 = 2 * it + 2, t3 = 2 * it + 3;
    bool nl = (it < 7);
    // ph0: q(A0,B0) t_even/buf0; stage t1.A1
    READA(0, 0); READB(0, 0);
    STG(1, 1, Asrc[1], 2 * it + 1);
    BAR1(); MFMA16(0, 0); BAR2();
    // ph1: q(A0,B1); stage t1.B0
    READB(1, 0);
    STG(1, 2, Bsrc[0], 2 * it + 1);
    BAR1(); MFMA16(0, 1); BAR2();
    // ph2: q(A1,B1); stage t2.A0
    READA(1, 0);
    if (nl) STG(0, 0, Asrc[0], t2);
    BAR1(); MFMA16(1, 1); BAR2();
    // ph3: q(A1,B0); stage t2.B1; vmcnt checkpoint
    READB(0, 0);
    if (nl) STG(0, 3, Bsrc[1], t2);
    BAR1(); MFMA16(1, 0);
    if (nl) { VMW(4); } else { VMW(0); }
    BAR2();
    // ph4: q(A0,B0) t_odd/buf1; stage t2.A1
    READA(0, 1); READB(0, 1);
    if (nl) STG(0, 1, Asrc[1], t2);
    BAR1(); MFMA16(0, 0); BAR2();
    // ph5: q(A0,B1); stage t2.B0
    READB(1, 1);
    if (nl) STG(0, 2, Bsrc[0], t2);
    BAR1(); MFMA16(0, 1); BAR2();
    // ph6: q(A1,B1); stage t3.A0
    READA(1, 1);
    if (nl) STG(1, 0, Asrc[0], t3);
    BAR1(); MFMA16(1, 1); BAR2();
    // ph7: q(A1,B0); stage t3.B1; vmcnt checkpoint
    READB(0, 1);
    if (nl) STG(1, 3, Bsrc[1], t3);
    BAR1(); MFMA16(1, 0);
    if (nl) { VMW(4); }
    BAR2();
  }

  // -------------------------- epilogue --------------------------
  if (n0 < 2048) {  // Q or K -> [B,H,T,64] bf16
    u16* dst = (n0 < 1024) ? qbuf : kbuf;
#pragma unroll
    for (int bh = 0; bh < 2; ++bh)
#pragma unroll
      for (int nfl = 0; nfl < 2; ++nfl) {
        int n = n0 + bh * 128 + wr * 32 + nfl * 16 + ln;
        float al = alphaf[n], bi = biasf[n];
        int nl2 = n & 1023;
        int h = nl2 >> 6, d = nl2 & 63;
#pragma unroll
        for (int ah = 0; ah < 2; ++ah)
#pragma unroll
          for (int mfl = 0; mfl < 4; ++mfl)
#pragma unroll
            for (int rg = 0; rg < 4; ++rg) {
              int m = m0 + ah * 128 + wq * 64 + mfl * 16 + g * 4 + rg;
              int b = m >> 11, t = m & 2047;
              dst[(((b * 16 + h) * 2048 + t) << 6) + d] =
                  bf16u(al * acc[ah * 4 + mfl][bh * 2 + nfl][rg] + bi);
            }
      }
  } else {  // V -> transpose via LDS -> [B,H,64,T], two 128-row passes
    u16* ldsT = reinterpret_cast<u16*>(smem);
    int b = m0 >> 11;
#pragma unroll
    for (int mh = 0; mh < 2; ++mh) {
      __syncthreads();
#pragma unroll
      for (int bh = 0; bh < 2; ++bh)
#pragma unroll
        for (int nfl = 0; nfl < 2; ++nfl) {
          int n = n0 + bh * 128 + wr * 32 + nfl * 16 + ln;
          float al = alphaf[n], bi = biasf[n];
          int nloc = bh * 128 + wr * 32 + nfl * 16 + ln;
#pragma unroll
          for (int mfl = 0; mfl < 4; ++mfl)
#pragma unroll
            for (int rg = 0; rg < 4; ++rg) {
              int mloc = wq * 64 + mfl * 16 + g * 4 + rg;
              ldsT[mloc * 260 + nloc] =
                  bf16u(al * acc[mh * 4 + mfl][bh * 2 + nfl][rg] + bi);
            }
        }
      __syncthreads();
      int dl = tid >> 1;            // 0..255 (n-col)
      int sh = (tid & 1) * 64;      // m-half within pass
      int nv = n0 - 2048 + dl;
      int h = nv >> 6, d = nv & 63;
      int s0 = (m0 & 2047) + mh * 128 + sh;
      u16* vdst = vtbuf + (((b * 16 + h) * 64 + d) << 11) + s0;
#pragma unroll
      for (int c8 = 0; c8 < 8; ++c8) {
        u16 t0 = ldsT[(sh + c8 * 8 + 0 - sh) * 260 + dl + (sh + c8 * 8) * 0];  // placeholder avoided below
        (void)t0;
        u16 e0 = ldsT[(sh + c8 * 8 + 0) * 260 + dl], e1 = ldsT[(sh + c8 * 8 + 1) * 260 + dl];
        u16 e2 = ldsT[(sh + c8 * 8 + 2) * 260 + dl], e3 = ldsT[(sh + c8 * 8 + 3) * 260 + dl];
        u16 e4 = ldsT[(sh + c8 * 8 + 4) * 260 + dl], e5 = ldsT[(sh + c8 * 8 + 5) * 260 + dl];
        u16 e6 = ldsT[(sh + c8 * 8 + 6) * 260 + dl], e7 = ldsT[(sh + c8 * 8 + 7) * 260 + dl];
        uint4 w = { pk(e0, e1), pk(e2, e3), pk(e4, e5), pk(e6, e7) };
        *reinterpret_cast<uint4*>(vdst + c8 * 8) = w;
      }
    }
  }
#undef HT
#undef STG
#undef READA
#undef READB
#undef MFMA16
#undef BAR1
#undef BAR2
#undef VMW
}

// ---------------------------------------------------------------------------
// GEMM v2 (R11, used for proj): 128x128 tile, BK=64, 4 waves, dbuf staging.
// ---------------------------------------------------------------------------
template <int MODE, int NX, int NWG>
__global__ __launch_bounds__(256) void k_gemm(
    const u16* __restrict__ A, const u16* __restrict__ Bw,
    const float* __restrict__ alphaf, const float* __restrict__ biasf,
    u16* __restrict__ qbuf, u16* __restrict__ kbuf, u16* __restrict__ vtbuf,
    float* __restrict__ outf) {
  __shared__ alignas(128) char smem[65536];
  int tid = threadIdx.x;
  int wave = tid >> 6, l = tid & 63, g = l >> 4, ln = l & 15;
  int wm = (wave >> 1) * 64, wn = (wave & 1) * 64;
  int wg = (blockIdx.x & 7) * (NWG / 8) + (blockIdx.x >> 3);
  int m0 = (wg / NX) * 128, n0 = (wg % NX) * 128;

  f32x4 acc[4][4];
#pragma unroll
  for (int i = 0; i < 4; ++i)
#pragma unroll
    for (int j = 0; j < 4; ++j) acc[i][j] = f32x4{0.f, 0.f, 0.f, 0.f};

  const char* Ab = reinterpret_cast<const char*>(A) + m0 * 2048;
  const char* Bb = reinterpret_cast<const char*>(Bw) + n0 * 2048;

  int soff[4];
#pragma unroll
  for (int i = 0; i < 4; ++i) {
    int P = i * 4096 + tid * 16;
    int r = P >> 7;
    int kc = ((P >> 4) & 7) ^ (r & 7);
    soff[i] = r * 2048 + kc * 16;
  }

#pragma unroll
  for (int i = 0; i < 4; ++i)
    gload16(Ab + soff[i], smem + i * 4096 + wave * 1024);
#pragma unroll
  for (int i = 0; i < 4; ++i)
    gload16(Bb + soff[i], smem + 16384 + i * 4096 + wave * 1024);
  __syncthreads();

  for (int ks = 0; ks < 16; ++ks) {
    int cb = ks & 1;
    if (ks < 15) {
      char* nb = smem + (cb ^ 1) * 32768;
      int kb0 = (ks + 1) * 128;
#pragma unroll
      for (int i = 0; i < 4; ++i)
        gload16(Ab + soff[i] + kb0, nb + i * 4096 + wave * 1024);
#pragma unroll
      for (int i = 0; i < 4; ++i)
        gload16(Bb + soff[i] + kb0, nb + 16384 + i * 4096 + wave * 1024);
    }
    const char* As = smem + cb * 32768;
    const char* Bs = As + 16384;
#pragma unroll
    for (int kk = 0; kk < 2; ++kk) {
      s16x8 af[4], bfr[4];
#pragma unroll
      for (int mf = 0; mf < 4; ++mf) {
        int r = wm + mf * 16 + ln;
        int kb = (kk * 64 + g * 16) ^ ((r & 7) << 4);
        af[mf] = *reinterpret_cast<const s16x8*>(As + r * 128 + kb);
      }
#pragma unroll
      for (int nf = 0; nf < 4; ++nf) {
        int r = wn + nf * 16 + ln;
        int kb = (kk * 64 + g * 16) ^ ((r & 7) << 4);
        bfr[nf] = *reinterpret_cast<const s16x8*>(Bs + r * 128 + kb);
      }
#pragma unroll
      for (int mf = 0; mf < 4; ++mf)
#pragma unroll
        for (int nf = 0; nf < 4; ++nf)
          acc[mf][nf] = __builtin_amdgcn_mfma_f32_16x16x32_bf16(af[mf], bfr[nf], acc[mf][nf], 0, 0, 0);
    }
    __syncthreads();
  }

  if (MODE == 0) {
    // (unused in this configuration)
  } else {
#pragma unroll
    for (int nf = 0; nf < 4; ++nf) {
      int n = n0 + wn + nf * 16 + ln;
      float al = alphaf[3072 + n], bi = biasf[3072 + n];
#pragma unroll
      for (int mf = 0; mf < 4; ++mf)
#pragma unroll
        for (int rg = 0; rg < 4; ++rg) {
          int m = m0 + wm + mf * 16 + g * 4 + rg;
          outf[m * 1024 + n] = al * acc[mf][nf][rg] + bi;
        }
    }
  }
}

// ---------------------------------------------------------------------------
// Flash attention v6 (R11 exact, best measured): 8 waves x 32 q-rows,
// grid 512, KVBLK=64, K-row permutation -> lane-local P, fixed m=0,
// ones-MFMA l, zero-conflict swizzle, single-op cvt_pk packing.
// ---------------------------------------------------------------------------
__global__ __launch_bounds__(512, 4) void k_attn(
    const u16* __restrict__ qb, const u16* __restrict__ kb,
    const u16* __restrict__ vtb, u16* __restrict__ yb) {
  __shared__ alignas(128) char smem[32768];
  int tid = threadIdx.x;
  int wave = tid >> 6, lane = tid & 63;
  int g = lane >> 4, ln = lane & 15;

  int wg = (blockIdx.x & 7) * 64 + (blockIdx.x >> 3);
  int bh = wg >> 3, qt = wg & 7;
  const char* Qg = reinterpret_cast<const char*>(qb) + bh * 262144;
  const char* Kg = reinterpret_cast<const char*>(kb) + bh * 262144;
  const char* Vg = reinterpret_cast<const char*>(vtb) + bh * 262144;

  int qrow = qt * 256 + wave * 32 + ln;
  const s16x8* Qr0 = reinterpret_cast<const s16x8*>(Qg + qrow * 128);
  const s16x8* Qr1 = reinterpret_cast<const s16x8*>(Qg + (qrow + 16) * 128);
  s16x8 qf[2][2];
  qf[0][0] = Qr0[g]; qf[0][1] = Qr0[g + 4];
  qf[1][0] = Qr1[g]; qf[1][1] = Qr1[g + 4];

  s16x8 ones;
#pragma unroll
  for (int i = 0; i < 8; ++i) ones[i] = (short)0x3F80;

  int r = tid >> 3, kc = tid & 7;
  int wr2 = (r & 3) | (((r >> 3) & 1) << 2);
  int swsrc = (kc ^ wr2) * 16;
  int ksrc = r * 128 + swsrc;
  int vsrc = r * 4096 + swsrc;

  int swK = (ln & 7) << 4;
  int swV = ((ln & 3) | (((ln >> 3) & 1) << 2)) << 4;

  f32x4 oacc[2][4];
#pragma unroll
  for (int s = 0; s < 2; ++s)
#pragma unroll
    for (int i = 0; i < 4; ++i) oacc[s][i] = f32x4{0.f, 0.f, 0.f, 0.f};
  f32x4 lacc[2];
  lacc[0] = f32x4{0.f, 0.f, 0.f, 0.f};
  lacc[1] = f32x4{0.f, 0.f, 0.f, 0.f};

  gload16(Kg + ksrc, smem + wave * 1024);
  gload16(Vg + vsrc, smem + 8192 + wave * 1024);
  __syncthreads();

  for (int st = 0; st < 32; ++st) {
    int cb = st & 1;
    if (st < 31) {
      int sb = (st + 1) * 64;
      char* nb = smem + (cb ^ 1) * 16384;
      gload16(Kg + sb * 128 + ksrc, nb + wave * 1024);
      gload16(Vg + sb * 2 + vsrc, nb + 8192 + wave * 1024);
    }
    const char* Kb = smem + cb * 16384;
    const char* Vb = Kb + 8192;

    f32x4 sacc[2][4];
#pragma unroll
    for (int s = 0; s < 2; ++s)
#pragma unroll
      for (int t = 0; t < 4; ++t) sacc[s][t] = f32x4{0.f, 0.f, 0.f, 0.f};
    __builtin_amdgcn_s_setprio(1);
#pragma unroll
    for (int kt = 0; kt < 2; ++kt) {
      int off = (kt * 64 + g * 16) ^ swK;
#pragma unroll
      for (int t = 0; t < 4; ++t) {
        int rho = 32 * (t & 1) + 8 * (ln >> 2) + 4 * (t >> 1) + (ln & 3);
        s16x8 kf = *reinterpret_cast<const s16x8*>(Kb + rho * 128 + off);
        sacc[0][t] = __builtin_amdgcn_mfma_f32_16x16x32_bf16(kf, qf[0][kt], sacc[0][t], 0, 0, 0);
        sacc[1][t] = __builtin_amdgcn_mfma_f32_16x16x32_bf16(kf, qf[1][kt], sacc[1][t], 0, 0, 0);
      }
    }
    __builtin_amdgcn_s_setprio(0);

    s16x8 pf[2][2];
#pragma unroll
    for (int s = 0; s < 2; ++s) {
      float p[4][4];
#pragma unroll
      for (int t = 0; t < 4; ++t)
#pragma unroll
        for (int rg = 0; rg < 4; ++rg)
          p[t][rg] = __builtin_amdgcn_exp2f(sacc[s][t][rg]);
#pragma unroll
      for (int kt = 0; kt < 2; ++kt) {
        u32x4 tw;
        tw[0] = cvtpk(p[kt][0],     p[kt][1]);
        tw[1] = cvtpk(p[kt][2],     p[kt][3]);
        tw[2] = cvtpk(p[kt + 2][0], p[kt + 2][1]);
        tw[3] = cvtpk(p[kt + 2][2], p[kt + 2][3]);
        pf[s][kt] = __builtin_bit_cast(s16x8, tw);
      }
    }

#pragma unroll
    for (int s = 0; s < 2; ++s)
#pragma unroll
      for (int kt = 0; kt < 2; ++kt)
        lacc[s] = __builtin_amdgcn_mfma_f32_16x16x32_bf16(ones, pf[s][kt], lacc[s], 0, 0, 0);

    __builtin_amdgcn_s_setprio(1);
#pragma unroll
    for (int kt = 0; kt < 2; ++kt) {
      int off = (kt * 64 + g * 16) ^ swV;
#pragma unroll
      for (int dt = 0; dt < 4; ++dt) {
        s16x8 vf = *reinterpret_cast<const s16x8*>(Vb + (dt * 16 + ln) * 128 + off);
        oacc[0][dt] = __builtin_amdgcn_mfma_f32_16x16x32_bf16(vf, pf[0][kt], oacc[0][dt], 0, 0, 0);
        oacc[1][dt] = __builtin_amdgcn_mfma_f32_16x16x32_bf16(vf, pf[1][kt], oacc[1][dt], 0, 0, 0);
      }
    }
    __builtin_amdgcn_s_setprio(0);
    __syncthreads();
  }

  int b = bh >> 4, h = bh & 15;
#pragma unroll
  for (int s = 0; s < 2; ++s) {
    float linv = 1.0f / lacc[s][0];
    u16* yrow = yb + (b * 2048 + qrow + s * 16) * 1024 + h * 64;
#pragma unroll
    for (int dt = 0; dt < 4; ++dt) {
      uint2 w;
      w.x = cvtpk(oacc[s][dt][0] * linv, oacc[s][dt][1] * linv);
      w.y = cvtpk(oacc[s][dt][2] * linv, oacc[s][dt][3] * linv);
      *reinterpret_cast<uint2*>(yrow + dt * 16 + g * 4) = w;
    }
  }
}

// ---------------------------------------------------------------------------
extern "C" void kernel_launch(void* const* d_in, const int* in_sizes, int n_in,
                              void* d_out, int out_size, void* d_ws, size_t ws_size,
                              hipStream_t stream) {
  (void)in_sizes; (void)n_in; (void)out_size; (void)ws_size;
  const float* x  = (const float*)d_in[0];
  const float* Wq = (const float*)d_in[1];
  const float* bq = (const float*)d_in[2];
  const float* Wk = (const float*)d_in[3];
  const float* bk = (const float*)d_in[4];
  const float* Wv = (const float*)d_in[5];
  const float* bv = (const float*)d_in[6];
  const float* Wp = (const float*)d_in[7];
  const float* bp = (const float*)d_in[8];

  char* ws = (char*)d_ws;
  u16*   xb    = (u16*)(ws);               // 16MB (reused as Y after attention)
  u16*   wbqkv = (u16*)(ws + 16777216);    // 6MB
  u16*   wbp   = (u16*)(ws + 23068672);    // 2MB
  float* alphaf = (float*)(ws + 25165824); // 16KB
  float* biasf  = (float*)(ws + 25182208); // 16KB
  u16*   vtbuf = (u16*)(ws + 25198592);    // 16MB
  u16*   ybuf  = xb;
  u16*   qbuf  = (u16*)d_out;              // d_out (32MB) as Q|K scratch
  u16*   kbuf  = (u16*)d_out + 8388608;
  float* outf  = (float*)d_out;

  k_prep<<<5120, 256, 0, stream>>>(x, xb, Wq, Wk, Wv, Wp, bq, bk, bv, bp, wbqkv, wbp, alphaf, biasf);
  k_gemm8<12, 384><<<384, 512, 0, stream>>>(xb, wbqkv, alphaf, biasf, qbuf, kbuf, vtbuf);
  k_attn<<<512, 512, 0, stream>>>(qbuf, kbuf, vtbuf, ybuf);
  k_gemm<1, 8, 512><<<512, 256, 0, stream>>>(ybuf, wbp, alphaf, biasf, nullptr, nullptr, nullptr, outf);
}

// Round 20
// 154.050 us; speedup vs baseline: 1.0385x; 1.0385x over previous
//
#include <hip/hip_runtime.h>
#include <hip/hip_bf16.h>

typedef short s16x8 __attribute__((ext_vector_type(8)));
typedef float f32x4 __attribute__((ext_vector_type(4)));
typedef unsigned u32x4 __attribute__((ext_vector_type(4)));
typedef unsigned short u16;

#define LOG2E 1.4426950408889634f
#define QSC (0.125f * LOG2E)   // softmax scale (Dh=64 -> 1/8) * log2(e), folded into alpha_q/bias_q

typedef __attribute__((address_space(3))) unsigned int lds_u32;
typedef __attribute__((address_space(1))) const unsigned int glb_u32;

static __device__ __forceinline__ void gload16(const void* g, void* l) {
  __builtin_amdgcn_global_load_lds((glb_u32*)g, (lds_u32*)l, 16, 0, 0);
}
static __device__ __forceinline__ u16 bf16u(float f) {
  unsigned u = __builtin_bit_cast(unsigned, f);
  return (u16)((u + 0x7FFFu + ((u >> 16) & 1u)) >> 16);  // RNE
}
static __device__ __forceinline__ unsigned pk(u16 a, u16 b) {
  return (unsigned)a | ((unsigned)b << 16);
}
// packed RNE f32x2 -> bf16x2, single HW op (no builtin on gfx950 - T12 recipe)
static __device__ __forceinline__ unsigned cvtpk(float lo, float hi) {
  unsigned d;
  asm("v_cvt_pk_bf16_f32 %0, %1, %2" : "=v"(d) : "v"(lo), "v"(hi));
  return d;
}
// header path (used only in non-hot prep)
static __device__ __forceinline__ unsigned pk2(float a, float b) {
  float2 f; f.x = a; f.y = b;
  __hip_bfloat162 h = __float22bfloat162_rn(f);
  unsigned r;
  __builtin_memcpy(&r, &h, 4);
  return r;
}

// ---------------------------------------------------------------------------
// Prep (merged): blocks 0..1023 binarize weights; blocks 1024..5119 cvt x.
// ---------------------------------------------------------------------------
__global__ __launch_bounds__(256) void k_prep(
    const float* __restrict__ x, u16* __restrict__ xb,
    const float* __restrict__ Wq, const float* __restrict__ Wk,
    const float* __restrict__ Wv, const float* __restrict__ Wp,
    const float* __restrict__ bq, const float* __restrict__ bk,
    const float* __restrict__ bv, const float* __restrict__ bp,
    u16* __restrict__ wbqkv, u16* __restrict__ wbp,
    float* __restrict__ alphaf, float* __restrict__ biasf) {
  if (blockIdx.x >= 1024) {
    int i = ((blockIdx.x - 1024) * 256 + threadIdx.x) * 8;
    float4 a = *reinterpret_cast<const float4*>(x + i);
    float4 b = *reinterpret_cast<const float4*>(x + i + 4);
    uint4 w = { pk2(a.x, a.y), pk2(a.z, a.w), pk2(b.x, b.y), pk2(b.z, b.w) };
    *reinterpret_cast<uint4*>(xb + i) = w;
    return;
  }
  int wave = threadIdx.x >> 6, lane = threadIdx.x & 63;
  int row = blockIdx.x * 4 + wave;
  const float* src; const float* bias; int r;
  if (row < 1024)      { src = Wq; bias = bq; r = row; }
  else if (row < 2048) { src = Wk; bias = bk; r = row - 1024; }
  else if (row < 3072) { src = Wv; bias = bv; r = row - 2048; }
  else                 { src = Wp; bias = bp; r = row - 3072; }
  const float4* s4 = reinterpret_cast<const float4*>(src + r * 1024);
  float4 v[4];
  float asum = 0.f;
#pragma unroll
  for (int i = 0; i < 4; ++i) {
    v[i] = s4[lane * 4 + i];
    asum += fabsf(v[i].x) + fabsf(v[i].y) + fabsf(v[i].z) + fabsf(v[i].w);
  }
#pragma unroll
  for (int m = 32; m >= 1; m >>= 1) asum += __shfl_xor(asum, m, 64);
  float alpha = asum * (1.0f / 1024.0f);

  u16 o[16];
#pragma unroll
  for (int i = 0; i < 4; ++i) {
    const float* f = reinterpret_cast<const float*>(&v[i]);
#pragma unroll
    for (int j = 0; j < 4; ++j) {
      float w = f[j];
      o[i * 4 + j] = (w > 0.f) ? (u16)0x3F80 : ((w < 0.f) ? (u16)0xBF80 : (u16)0);
    }
  }
  u16* dst = (row < 3072 ? wbqkv + row * 1024 : wbp + (row - 3072) * 1024) + lane * 16;
  uint4 w0 = { pk(o[0],o[1]), pk(o[2],o[3]), pk(o[4],o[5]), pk(o[6],o[7]) };
  uint4 w1 = { pk(o[8],o[9]), pk(o[10],o[11]), pk(o[12],o[13]), pk(o[14],o[15]) };
  reinterpret_cast<uint4*>(dst)[0] = w0;
  reinterpret_cast<uint4*>(dst)[1] = w1;
  if (lane == 0) {
    float sc = (row < 1024) ? QSC : 1.0f;
    alphaf[row] = alpha * sc;
    biasf[row]  = bias[r] * sc;
  }
}

// ---------------------------------------------------------------------------
// GEMM v2 (R11 exact, best measured): 128x128 tile, BK=64, 4 waves,
// 16x16x32 MFMA, XCD-swizzled grid, double-buffered staging: issue next
// K-step's global_load_lds into buf^1 before computing current buf, single
// barrier per step.
// ---------------------------------------------------------------------------
template <int MODE, int NX, int NWG>
__global__ __launch_bounds__(256) void k_gemm(
    const u16* __restrict__ A, const u16* __restrict__ Bw,
    const float* __restrict__ alphaf, const float* __restrict__ biasf,
    u16* __restrict__ qbuf, u16* __restrict__ kbuf, u16* __restrict__ vtbuf,
    float* __restrict__ outf) {
  __shared__ alignas(128) char smem[65536];  // 2 x (A 16K | B 16K)
  int tid = threadIdx.x;
  int wave = tid >> 6, l = tid & 63, g = l >> 4, ln = l & 15;
  int wm = (wave >> 1) * 64, wn = (wave & 1) * 64;
  int wg = (blockIdx.x & 7) * (NWG / 8) + (blockIdx.x >> 3);  // XCD swizzle
  int m0 = (wg / NX) * 128, n0 = (wg % NX) * 128;

  f32x4 acc[4][4];
#pragma unroll
  for (int i = 0; i < 4; ++i)
#pragma unroll
    for (int j = 0; j < 4; ++j) acc[i][j] = f32x4{0.f, 0.f, 0.f, 0.f};

  const char* Ab = reinterpret_cast<const char*>(A) + m0 * 2048;
  const char* Bb = reinterpret_cast<const char*>(Bw) + n0 * 2048;

  int soff[4];
#pragma unroll
  for (int i = 0; i < 4; ++i) {
    int P = i * 4096 + tid * 16;
    int r = P >> 7;
    int kc = ((P >> 4) & 7) ^ (r & 7);
    soff[i] = r * 2048 + kc * 16;
  }

  // prologue: stage K-step 0 into buf0
#pragma unroll
  for (int i = 0; i < 4; ++i)
    gload16(Ab + soff[i], smem + i * 4096 + wave * 1024);
#pragma unroll
  for (int i = 0; i < 4; ++i)
    gload16(Bb + soff[i], smem + 16384 + i * 4096 + wave * 1024);
  __syncthreads();

  for (int ks = 0; ks < 16; ++ks) {
    int cb = ks & 1;
    if (ks < 15) {  // prefetch next K-step into the other buffer
      char* nb = smem + (cb ^ 1) * 32768;
      int kb0 = (ks + 1) * 128;
#pragma unroll
      for (int i = 0; i < 4; ++i)
        gload16(Ab + soff[i] + kb0, nb + i * 4096 + wave * 1024);
#pragma unroll
      for (int i = 0; i < 4; ++i)
        gload16(Bb + soff[i] + kb0, nb + 16384 + i * 4096 + wave * 1024);
    }
    const char* As = smem + cb * 32768;
    const char* Bs = As + 16384;
#pragma unroll
    for (int kk = 0; kk < 2; ++kk) {
      s16x8 af[4], bfr[4];
#pragma unroll
      for (int mf = 0; mf < 4; ++mf) {
        int r = wm + mf * 16 + ln;
        int kb = (kk * 64 + g * 16) ^ ((r & 7) << 4);
        af[mf] = *reinterpret_cast<const s16x8*>(As + r * 128 + kb);
      }
#pragma unroll
      for (int nf = 0; nf < 4; ++nf) {
        int r = wn + nf * 16 + ln;
        int kb = (kk * 64 + g * 16) ^ ((r & 7) << 4);
        bfr[nf] = *reinterpret_cast<const s16x8*>(Bs + r * 128 + kb);
      }
#pragma unroll
      for (int mf = 0; mf < 4; ++mf)
#pragma unroll
        for (int nf = 0; nf < 4; ++nf)
          acc[mf][nf] = __builtin_amdgcn_mfma_f32_16x16x32_bf16(af[mf], bfr[nf], acc[mf][nf], 0, 0, 0);
    }
    __syncthreads();  // drains prefetch vmcnt; buf swap safe
  }

  if (MODE == 0) {
    if (n0 < 2048) {
      u16* dst = (n0 < 1024) ? qbuf : kbuf;
#pragma unroll
      for (int nf = 0; nf < 4; ++nf) {
        int n = n0 + wn + nf * 16 + ln;
        float al = alphaf[n], bi = biasf[n];
        int nl = n & 1023;
        int h = nl >> 6, d = nl & 63;
#pragma unroll
        for (int mf = 0; mf < 4; ++mf)
#pragma unroll
          for (int rg = 0; rg < 4; ++rg) {
            int m = m0 + wm + mf * 16 + g * 4 + rg;
            int b = m >> 11, t = m & 2047;
            dst[(((b * 16 + h) * 2048 + t) << 6) + d] = bf16u(al * acc[mf][nf][rg] + bi);
          }
      }
    } else {
      u16* ldsT = reinterpret_cast<u16*>(smem);
#pragma unroll
      for (int nf = 0; nf < 4; ++nf) {
        int n = n0 + wn + nf * 16 + ln;
        float al = alphaf[n], bi = biasf[n];
        int nloc = wn + nf * 16 + ln;
#pragma unroll
        for (int mf = 0; mf < 4; ++mf)
#pragma unroll
          for (int rg = 0; rg < 4; ++rg) {
            int mloc = wm + mf * 16 + g * 4 + rg;
            ldsT[mloc * 132 + nloc] = bf16u(al * acc[mf][nf][rg] + bi);
          }
      }
      __syncthreads();
      int dl = tid >> 1;
      int sh = (tid & 1) * 64;
      int nv = n0 - 2048 + dl;
      int h = nv >> 6, d = nv & 63;
      int b = m0 >> 11;
      int s0 = (m0 & 2047) + sh;
      u16* vdst = vtbuf + (((b * 16 + h) * 64 + d) << 11) + s0;
#pragma unroll
      for (int c8 = 0; c8 < 8; ++c8) {
        u16 t0 = ldsT[(sh + c8 * 8 + 0) * 132 + dl], t1 = ldsT[(sh + c8 * 8 + 1) * 132 + dl];
        u16 t2 = ldsT[(sh + c8 * 8 + 2) * 132 + dl], t3 = ldsT[(sh + c8 * 8 + 3) * 132 + dl];
        u16 t4 = ldsT[(sh + c8 * 8 + 4) * 132 + dl], t5 = ldsT[(sh + c8 * 8 + 5) * 132 + dl];
        u16 t6 = ldsT[(sh + c8 * 8 + 6) * 132 + dl], t7 = ldsT[(sh + c8 * 8 + 7) * 132 + dl];
        uint4 w = { pk(t0, t1), pk(t2, t3), pk(t4, t5), pk(t6, t7) };
        *reinterpret_cast<uint4*>(vdst + c8 * 8) = w;
      }
    }
  } else {
#pragma unroll
    for (int nf = 0; nf < 4; ++nf) {
      int n = n0 + wn + nf * 16 + ln;
      float al = alphaf[3072 + n], bi = biasf[3072 + n];
#pragma unroll
      for (int mf = 0; mf < 4; ++mf)
#pragma unroll
        for (int rg = 0; rg < 4; ++rg) {
          int m = m0 + wm + mf * 16 + g * 4 + rg;
          outf[m * 1024 + n] = al * acc[mf][nf][rg] + bi;
        }
    }
  }
}

// ---------------------------------------------------------------------------
// Flash attention v6 (R11 exact, best measured: 70.2us, 0 bank conflicts):
// 8 waves x 32 q-rows, grid 512, KVBLK=64, K-row permutation -> lane-local P,
// fixed m=0, ones-MFMA l, zero-conflict swizzle, single-op cvt_pk packing.
// ---------------------------------------------------------------------------
__global__ __launch_bounds__(512, 4) void k_attn(
    const u16* __restrict__ qb, const u16* __restrict__ kb,
    const u16* __restrict__ vtb, u16* __restrict__ yb) {
  __shared__ alignas(128) char smem[32768];  // [buf0: K 8K | V 8K][buf1: ...]
  int tid = threadIdx.x;
  int wave = tid >> 6, lane = tid & 63;
  int g = lane >> 4, ln = lane & 15;

  // XCD swizzle: 8 q-tiles of one bh on one XCD (K/V of 8 heads = 4MB = L2)
  int wg = (blockIdx.x & 7) * 64 + (blockIdx.x >> 3);
  int bh = wg >> 3, qt = wg & 7;
  const char* Qg = reinterpret_cast<const char*>(qb) + bh * 262144;
  const char* Kg = reinterpret_cast<const char*>(kb) + bh * 262144;
  const char* Vg = reinterpret_cast<const char*>(vtb) + bh * 262144;  // [64 d][2048 s]

  // Q fragments: lane (g,ln) holds Q[qrow][k = 32kt + 8g + j]; 2 q-sets
  int qrow = qt * 256 + wave * 32 + ln;
  const s16x8* Qr0 = reinterpret_cast<const s16x8*>(Qg + qrow * 128);
  const s16x8* Qr1 = reinterpret_cast<const s16x8*>(Qg + (qrow + 16) * 128);
  s16x8 qf[2][2];
  qf[0][0] = Qr0[g]; qf[0][1] = Qr0[g + 4];
  qf[1][0] = Qr1[g]; qf[1][1] = Qr1[g + 4];

  s16x8 ones;
#pragma unroll
  for (int i = 0; i < 8; ++i) ones[i] = (short)0x3F80;

  // staging offsets: source pre-swizzled with w(r) = (r&3)|(bit3(r)<<2)
  int r = tid >> 3, kc = tid & 7;
  int wr = (r & 3) | (((r >> 3) & 1) << 2);
  int swsrc = (kc ^ wr) * 16;
  int ksrc = r * 128 + swsrc;
  int vsrc = r * 4096 + swsrc;

  // read-side XOR bytes
  int swK = (ln & 7) << 4;                              // w(rho) = ln&7
  int swV = ((ln & 3) | (((ln >> 3) & 1) << 2)) << 4;   // w(dt*16+ln)

  f32x4 oacc[2][4];
#pragma unroll
  for (int s = 0; s < 2; ++s)
#pragma unroll
    for (int i = 0; i < 4; ++i) oacc[s][i] = f32x4{0.f, 0.f, 0.f, 0.f};
  f32x4 lacc[2];
  lacc[0] = f32x4{0.f, 0.f, 0.f, 0.f};
  lacc[1] = f32x4{0.f, 0.f, 0.f, 0.f};

  // prologue: stage tile 0 into buf0
  gload16(Kg + ksrc, smem + wave * 1024);
  gload16(Vg + vsrc, smem + 8192 + wave * 1024);
  __syncthreads();

  for (int st = 0; st < 32; ++st) {
    int cb = st & 1;
    if (st < 31) {  // prefetch next tile into the other buffer
      int sb = (st + 1) * 64;
      char* nb = smem + (cb ^ 1) * 16384;
      gload16(Kg + sb * 128 + ksrc, nb + wave * 1024);
      gload16(Vg + sb * 2 + vsrc, nb + 8192 + wave * 1024);
    }
    const char* Kb = smem + cb * 16384;
    const char* Vb = Kb + 8192;

    // S^T = mfma(K,Q) with permuted K rows:
    // sacc[set][t] reg rg = S[q][s = 32(t&1) + 8g + 4(t>>1) + rg]
    f32x4 sacc[2][4];
#pragma unroll
    for (int s = 0; s < 2; ++s)
#pragma unroll
      for (int t = 0; t < 4; ++t) sacc[s][t] = f32x4{0.f, 0.f, 0.f, 0.f};
    __builtin_amdgcn_s_setprio(1);
#pragma unroll
    for (int kt = 0; kt < 2; ++kt) {
      int off = (kt * 64 + g * 16) ^ swK;
#pragma unroll
      for (int t = 0; t < 4; ++t) {
        int rho = 32 * (t & 1) + 8 * (ln >> 2) + 4 * (t >> 1) + (ln & 3);
        s16x8 kf = *reinterpret_cast<const s16x8*>(Kb + rho * 128 + off);
        sacc[0][t] = __builtin_amdgcn_mfma_f32_16x16x32_bf16(kf, qf[0][kt], sacc[0][t], 0, 0, 0);
        sacc[1][t] = __builtin_amdgcn_mfma_f32_16x16x32_bf16(kf, qf[1][kt], sacc[1][t], 0, 0, 0);
      }
    }
    __builtin_amdgcn_s_setprio(0);

    // P = exp2(S) (m fixed 0) -> lane-local PV B-fragments (no LDS)
    s16x8 pf[2][2];
#pragma unroll
    for (int s = 0; s < 2; ++s) {
      float p[4][4];
#pragma unroll
      for (int t = 0; t < 4; ++t)
#pragma unroll
        for (int rg = 0; rg < 4; ++rg)
          p[t][rg] = __builtin_amdgcn_exp2f(sacc[s][t][rg]);
#pragma unroll
      for (int kt = 0; kt < 2; ++kt) {
        u32x4 tw;
        tw[0] = cvtpk(p[kt][0],     p[kt][1]);
        tw[1] = cvtpk(p[kt][2],     p[kt][3]);
        tw[2] = cvtpk(p[kt + 2][0], p[kt + 2][1]);
        tw[3] = cvtpk(p[kt + 2][2], p[kt + 2][3]);
        pf[s][kt] = __builtin_bit_cast(s16x8, tw);
      }
    }

    // l += ones . P  (A=ones: layout-independent row sums into lacc[set][rg])
#pragma unroll
    for (int s = 0; s < 2; ++s)
#pragma unroll
      for (int kt = 0; kt < 2; ++kt)
        lacc[s] = __builtin_amdgcn_mfma_f32_16x16x32_bf16(ones, pf[s][kt], lacc[s], 0, 0, 0);

    // O^T += mfma(V,P): V frag read once, feeds both q-sets
    __builtin_amdgcn_s_setprio(1);
#pragma unroll
    for (int kt = 0; kt < 2; ++kt) {
      int off = (kt * 64 + g * 16) ^ swV;
#pragma unroll
      for (int dt = 0; dt < 4; ++dt) {
        s16x8 vf = *reinterpret_cast<const s16x8*>(Vb + (dt * 16 + ln) * 128 + off);
        oacc[0][dt] = __builtin_amdgcn_mfma_f32_16x16x32_bf16(vf, pf[0][kt], oacc[0][dt], 0, 0, 0);
        oacc[1][dt] = __builtin_amdgcn_mfma_f32_16x16x32_bf16(vf, pf[1][kt], oacc[1][dt], 0, 0, 0);
      }
    }
    __builtin_amdgcn_s_setprio(0);
    __syncthreads();  // drains vmcnt (prefetch) + lgkm; buf swap safe
  }

  // epilogue: y[b, t, h*64 + d] = O[d][q]/l, d = 16dt + 4g + rg
  int b = bh >> 4, h = bh & 15;
#pragma unroll
  for (int s = 0; s < 2; ++s) {
    float linv = 1.0f / lacc[s][0];
    u16* yrow = yb + (b * 2048 + qrow + s * 16) * 1024 + h * 64;
#pragma unroll
    for (int dt = 0; dt < 4; ++dt) {
      uint2 w;
      w.x = cvtpk(oacc[s][dt][0] * linv, oacc[s][dt][1] * linv);
      w.y = cvtpk(oacc[s][dt][2] * linv, oacc[s][dt][3] * linv);
      *reinterpret_cast<uint2*>(yrow + dt * 16 + g * 4) = w;
    }
  }
}

// ---------------------------------------------------------------------------
extern "C" void kernel_launch(void* const* d_in, const int* in_sizes, int n_in,
                              void* d_out, int out_size, void* d_ws, size_t ws_size,
                              hipStream_t stream) {
  (void)in_sizes; (void)n_in; (void)out_size; (void)ws_size;
  const float* x  = (const float*)d_in[0];
  const float* Wq = (const float*)d_in[1];
  const float* bq = (const float*)d_in[2];
  const float* Wk = (const float*)d_in[3];
  const float* bk = (const float*)d_in[4];
  const float* Wv = (const float*)d_in[5];
  const float* bv = (const float*)d_in[6];
  const float* Wp = (const float*)d_in[7];
  const float* bp = (const float*)d_in[8];

  char* ws = (char*)d_ws;
  u16*   xb    = (u16*)(ws);               // 16MB (reused as Y after attention)
  u16*   wbqkv = (u16*)(ws + 16777216);    // 6MB
  u16*   wbp   = (u16*)(ws + 23068672);    // 2MB
  float* alphaf = (float*)(ws + 25165824); // 16KB
  float* biasf  = (float*)(ws + 25182208); // 16KB
  u16*   vtbuf = (u16*)(ws + 25198592);    // 16MB
  u16*   ybuf  = xb;
  u16*   qbuf  = (u16*)d_out;              // d_out (32MB) as Q|K scratch
  u16*   kbuf  = (u16*)d_out + 8388608;
  float* outf  = (float*)d_out;

  k_prep<<<5120, 256, 0, stream>>>(x, xb, Wq, Wk, Wv, Wp, bq, bk, bv, bp, wbqkv, wbp, alphaf, biasf);
  k_gemm<0, 24, 1536><<<1536, 256, 0, stream>>>(xb, wbqkv, alphaf, biasf, qbuf, kbuf, vtbuf, nullptr);
  k_attn<<<512, 512, 0, stream>>>(qbuf, kbuf, vtbuf, ybuf);
  k_gemm<1, 8, 512><<<512, 256, 0, stream>>>(ybuf, wbp, alphaf, biasf, nullptr, nullptr, nullptr, outf);
}

// Round 21
// 153.228 us; speedup vs baseline: 1.0441x; 1.0054x over previous
//
#include <hip/hip_runtime.h>
#include <hip/hip_bf16.h>

typedef short s16x8 __attribute__((ext_vector_type(8)));
typedef float f32x4 __attribute__((ext_vector_type(4)));
typedef unsigned u32x4 __attribute__((ext_vector_type(4)));
typedef unsigned short u16;

#define LOG2E 1.4426950408889634f
#define QSC (0.125f * LOG2E)   // softmax scale (Dh=64 -> 1/8) * log2(e), folded into alpha_q/bias_q

typedef __attribute__((address_space(3))) unsigned int lds_u32;
typedef __attribute__((address_space(1))) const unsigned int glb_u32;

static __device__ __forceinline__ void gload16(const void* g, void* l) {
  __builtin_amdgcn_global_load_lds((glb_u32*)g, (lds_u32*)l, 16, 0, 0);
}
static __device__ __forceinline__ u16 bf16u(float f) {
  unsigned u = __builtin_bit_cast(unsigned, f);
  return (u16)((u + 0x7FFFu + ((u >> 16) & 1u)) >> 16);  // RNE
}
static __device__ __forceinline__ unsigned pk(u16 a, u16 b) {
  return (unsigned)a | ((unsigned)b << 16);
}
// packed RNE f32x2 -> bf16x2, single HW op (no builtin on gfx950 - T12 recipe)
static __device__ __forceinline__ unsigned cvtpk(float lo, float hi) {
  unsigned d;
  asm("v_cvt_pk_bf16_f32 %0, %1, %2" : "=v"(d) : "v"(lo), "v"(hi));
  return d;
}
// header path (used only in non-hot prep)
static __device__ __forceinline__ unsigned pk2(float a, float b) {
  float2 f; f.x = a; f.y = b;
  __hip_bfloat162 h = __float22bfloat162_rn(f);
  unsigned r;
  __builtin_memcpy(&r, &h, 4);
  return r;
}

// ---------------------------------------------------------------------------
// Prep (merged): blocks 0..1023 binarize weights; blocks 1024..5119 cvt x.
// ---------------------------------------------------------------------------
__global__ __launch_bounds__(256) void k_prep(
    const float* __restrict__ x, u16* __restrict__ xb,
    const float* __restrict__ Wq, const float* __restrict__ Wk,
    const float* __restrict__ Wv, const float* __restrict__ Wp,
    const float* __restrict__ bq, const float* __restrict__ bk,
    const float* __restrict__ bv, const float* __restrict__ bp,
    u16* __restrict__ wbqkv, u16* __restrict__ wbp,
    float* __restrict__ alphaf, float* __restrict__ biasf) {
  if (blockIdx.x >= 1024) {
    int i = ((blockIdx.x - 1024) * 256 + threadIdx.x) * 8;
    float4 a = *reinterpret_cast<const float4*>(x + i);
    float4 b = *reinterpret_cast<const float4*>(x + i + 4);
    uint4 w = { pk2(a.x, a.y), pk2(a.z, a.w), pk2(b.x, b.y), pk2(b.z, b.w) };
    *reinterpret_cast<uint4*>(xb + i) = w;
    return;
  }
  int wave = threadIdx.x >> 6, lane = threadIdx.x & 63;
  int row = blockIdx.x * 4 + wave;
  const float* src; const float* bias; int r;
  if (row < 1024)      { src = Wq; bias = bq; r = row; }
  else if (row < 2048) { src = Wk; bias = bk; r = row - 1024; }
  else if (row < 3072) { src = Wv; bias = bv; r = row - 2048; }
  else                 { src = Wp; bias = bp; r = row - 3072; }
  const float4* s4 = reinterpret_cast<const float4*>(src + r * 1024);
  float4 v[4];
  float asum = 0.f;
#pragma unroll
  for (int i = 0; i < 4; ++i) {
    v[i] = s4[lane * 4 + i];
    asum += fabsf(v[i].x) + fabsf(v[i].y) + fabsf(v[i].z) + fabsf(v[i].w);
  }
#pragma unroll
  for (int m = 32; m >= 1; m >>= 1) asum += __shfl_xor(asum, m, 64);
  float alpha = asum * (1.0f / 1024.0f);

  u16 o[16];
#pragma unroll
  for (int i = 0; i < 4; ++i) {
    const float* f = reinterpret_cast<const float*>(&v[i]);
#pragma unroll
    for (int j = 0; j < 4; ++j) {
      float w = f[j];
      o[i * 4 + j] = (w > 0.f) ? (u16)0x3F80 : ((w < 0.f) ? (u16)0xBF80 : (u16)0);
    }
  }
  u16* dst = (row < 3072 ? wbqkv + row * 1024 : wbp + (row - 3072) * 1024) + lane * 16;
  uint4 w0 = { pk(o[0],o[1]), pk(o[2],o[3]), pk(o[4],o[5]), pk(o[6],o[7]) };
  uint4 w1 = { pk(o[8],o[9]), pk(o[10],o[11]), pk(o[12],o[13]), pk(o[14],o[15]) };
  reinterpret_cast<uint4*>(dst)[0] = w0;
  reinterpret_cast<uint4*>(dst)[1] = w1;
  if (lane == 0) {
    float sc = (row < 1024) ? QSC : 1.0f;
    alphaf[row] = alpha * sc;
    biasf[row]  = bias[r] * sc;
  }
}

// ---------------------------------------------------------------------------
// GEMM v2 (R11 K-loop, best measured) + optional SUPER tile mapping:
// SUPER=1 (gemm0): xcd owns m-tiles xcd*8..+7; within-XCD blocks advance in
// groups of 32 = 8m x 4n -> concurrent L2 working set = A 2MB + B 1MB < 4MB
// (R20 counters: FETCH 118MB vs 22MB ideal = B working set 6MB missing L2;
// per-step drain eats fabric latency). Pure permutation of block->tile ->
// bit-identical output.
// ---------------------------------------------------------------------------
template <int MODE, int NX, int NWG, int SUPER>
__global__ __launch_bounds__(256) void k_gemm(
    const u16* __restrict__ A, const u16* __restrict__ Bw,
    const float* __restrict__ alphaf, const float* __restrict__ biasf,
    u16* __restrict__ qbuf, u16* __restrict__ kbuf, u16* __restrict__ vtbuf,
    float* __restrict__ outf) {
  __shared__ alignas(128) char smem[65536];  // 2 x (A 16K | B 16K)
  int tid = threadIdx.x;
  int wave = tid >> 6, l = tid & 63, g = l >> 4, ln = l & 15;
  int wm = (wave >> 1) * 64, wn = (wave & 1) * 64;
  int m0, n0;
  if (SUPER) {
    int xcd = blockIdx.x & 7, idx = blockIdx.x >> 3;
    int grp = idx >> 5, wi = idx & 31;
    m0 = (xcd * 8 + (wi & 7)) * 128;    // 0..63
    n0 = (grp * 4 + (wi >> 3)) * 128;   // 0..23
  } else {
    int wg = (blockIdx.x & 7) * (NWG / 8) + (blockIdx.x >> 3);  // XCD swizzle
    m0 = (wg / NX) * 128;
    n0 = (wg % NX) * 128;
  }

  f32x4 acc[4][4];
#pragma unroll
  for (int i = 0; i < 4; ++i)
#pragma unroll
    for (int j = 0; j < 4; ++j) acc[i][j] = f32x4{0.f, 0.f, 0.f, 0.f};

  const char* Ab = reinterpret_cast<const char*>(A) + m0 * 2048;
  const char* Bb = reinterpret_cast<const char*>(Bw) + n0 * 2048;

  int soff[4];
#pragma unroll
  for (int i = 0; i < 4; ++i) {
    int P = i * 4096 + tid * 16;
    int r = P >> 7;
    int kc = ((P >> 4) & 7) ^ (r & 7);
    soff[i] = r * 2048 + kc * 16;
  }

  // prologue: stage K-step 0 into buf0
#pragma unroll
  for (int i = 0; i < 4; ++i)
    gload16(Ab + soff[i], smem + i * 4096 + wave * 1024);
#pragma unroll
  for (int i = 0; i < 4; ++i)
    gload16(Bb + soff[i], smem + 16384 + i * 4096 + wave * 1024);
  __syncthreads();

  for (int ks = 0; ks < 16; ++ks) {
    int cb = ks & 1;
    if (ks < 15) {  // prefetch next K-step into the other buffer
      char* nb = smem + (cb ^ 1) * 32768;
      int kb0 = (ks + 1) * 128;
#pragma unroll
      for (int i = 0; i < 4; ++i)
        gload16(Ab + soff[i] + kb0, nb + i * 4096 + wave * 1024);
#pragma unroll
      for (int i = 0; i < 4; ++i)
        gload16(Bb + soff[i] + kb0, nb + 16384 + i * 4096 + wave * 1024);
    }
    const char* As = smem + cb * 32768;
    const char* Bs = As + 16384;
#pragma unroll
    for (int kk = 0; kk < 2; ++kk) {
      s16x8 af[4], bfr[4];
#pragma unroll
      for (int mf = 0; mf < 4; ++mf) {
        int r = wm + mf * 16 + ln;
        int kb = (kk * 64 + g * 16) ^ ((r & 7) << 4);
        af[mf] = *reinterpret_cast<const s16x8*>(As + r * 128 + kb);
      }
#pragma unroll
      for (int nf = 0; nf < 4; ++nf) {
        int r = wn + nf * 16 + ln;
        int kb = (kk * 64 + g * 16) ^ ((r & 7) << 4);
        bfr[nf] = *reinterpret_cast<const s16x8*>(Bs + r * 128 + kb);
      }
#pragma unroll
      for (int mf = 0; mf < 4; ++mf)
#pragma unroll
        for (int nf = 0; nf < 4; ++nf)
          acc[mf][nf] = __builtin_amdgcn_mfma_f32_16x16x32_bf16(af[mf], bfr[nf], acc[mf][nf], 0, 0, 0);
    }
    __syncthreads();  // drains prefetch vmcnt; buf swap safe
  }

  if (MODE == 0) {
    if (n0 < 2048) {
      u16* dst = (n0 < 1024) ? qbuf : kbuf;
#pragma unroll
      for (int nf = 0; nf < 4; ++nf) {
        int n = n0 + wn + nf * 16 + ln;
        float al = alphaf[n], bi = biasf[n];
        int nl = n & 1023;
        int h = nl >> 6, d = nl & 63;
#pragma unroll
        for (int mf = 0; mf < 4; ++mf)
#pragma unroll
          for (int rg = 0; rg < 4; ++rg) {
            int m = m0 + wm + mf * 16 + g * 4 + rg;
            int b = m >> 11, t = m & 2047;
            dst[(((b * 16 + h) * 2048 + t) << 6) + d] = bf16u(al * acc[mf][nf][rg] + bi);
          }
      }
    } else {
      u16* ldsT = reinterpret_cast<u16*>(smem);
#pragma unroll
      for (int nf = 0; nf < 4; ++nf) {
        int n = n0 + wn + nf * 16 + ln;
        float al = alphaf[n], bi = biasf[n];
        int nloc = wn + nf * 16 + ln;
#pragma unroll
        for (int mf = 0; mf < 4; ++mf)
#pragma unroll
          for (int rg = 0; rg < 4; ++rg) {
            int mloc = wm + mf * 16 + g * 4 + rg;
            ldsT[mloc * 132 + nloc] = bf16u(al * acc[mf][nf][rg] + bi);
          }
      }
      __syncthreads();
      int dl = tid >> 1;
      int sh = (tid & 1) * 64;
      int nv = n0 - 2048 + dl;
      int h = nv >> 6, d = nv & 63;
      int b = m0 >> 11;
      int s0 = (m0 & 2047) + sh;
      u16* vdst = vtbuf + (((b * 16 + h) * 64 + d) << 11) + s0;
#pragma unroll
      for (int c8 = 0; c8 < 8; ++c8) {
        u16 t0 = ldsT[(sh + c8 * 8 + 0) * 132 + dl], t1 = ldsT[(sh + c8 * 8 + 1) * 132 + dl];
        u16 t2 = ldsT[(sh + c8 * 8 + 2) * 132 + dl], t3 = ldsT[(sh + c8 * 8 + 3) * 132 + dl];
        u16 t4 = ldsT[(sh + c8 * 8 + 4) * 132 + dl], t5 = ldsT[(sh + c8 * 8 + 5) * 132 + dl];
        u16 t6 = ldsT[(sh + c8 * 8 + 6) * 132 + dl], t7 = ldsT[(sh + c8 * 8 + 7) * 132 + dl];
        uint4 w = { pk(t0, t1), pk(t2, t3), pk(t4, t5), pk(t6, t7) };
        *reinterpret_cast<uint4*>(vdst + c8 * 8) = w;
      }
    }
  } else {
#pragma unroll
    for (int nf = 0; nf < 4; ++nf) {
      int n = n0 + wn + nf * 16 + ln;
      float al = alphaf[3072 + n], bi = biasf[3072 + n];
#pragma unroll
      for (int mf = 0; mf < 4; ++mf)
#pragma unroll
        for (int rg = 0; rg < 4; ++rg) {
          int m = m0 + wm + mf * 16 + g * 4 + rg;
          outf[m * 1024 + n] = al * acc[mf][nf][rg] + bi;
        }
    }
  }
}

// ---------------------------------------------------------------------------
// Flash attention v6 (R11 exact, best measured: 70.2us, 0 bank conflicts):
// 8 waves x 32 q-rows, grid 512, KVBLK=64, K-row permutation -> lane-local P,
// fixed m=0, ones-MFMA l, zero-conflict swizzle, single-op cvt_pk packing.
// ---------------------------------------------------------------------------
__global__ __launch_bounds__(512, 4) void k_attn(
    const u16* __restrict__ qb, const u16* __restrict__ kb,
    const u16* __restrict__ vtb, u16* __restrict__ yb) {
  __shared__ alignas(128) char smem[32768];  // [buf0: K 8K | V 8K][buf1: ...]
  int tid = threadIdx.x;
  int wave = tid >> 6, lane = tid & 63;
  int g = lane >> 4, ln = lane & 15;

  // XCD swizzle: 8 q-tiles of one bh on one XCD (K/V of 8 heads = 4MB = L2)
  int wg = (blockIdx.x & 7) * 64 + (blockIdx.x >> 3);
  int bh = wg >> 3, qt = wg & 7;
  const char* Qg = reinterpret_cast<const char*>(qb) + bh * 262144;
  const char* Kg = reinterpret_cast<const char*>(kb) + bh * 262144;
  const char* Vg = reinterpret_cast<const char*>(vtb) + bh * 262144;  // [64 d][2048 s]

  // Q fragments: lane (g,ln) holds Q[qrow][k = 32kt + 8g + j]; 2 q-sets
  int qrow = qt * 256 + wave * 32 + ln;
  const s16x8* Qr0 = reinterpret_cast<const s16x8*>(Qg + qrow * 128);
  const s16x8* Qr1 = reinterpret_cast<const s16x8*>(Qg + (qrow + 16) * 128);
  s16x8 qf[2][2];
  qf[0][0] = Qr0[g]; qf[0][1] = Qr0[g + 4];
  qf[1][0] = Qr1[g]; qf[1][1] = Qr1[g + 4];

  s16x8 ones;
#pragma unroll
  for (int i = 0; i < 8; ++i) ones[i] = (short)0x3F80;

  // staging offsets: source pre-swizzled with w(r) = (r&3)|(bit3(r)<<2)
  int r = tid >> 3, kc = tid & 7;
  int wr = (r & 3) | (((r >> 3) & 1) << 2);
  int swsrc = (kc ^ wr) * 16;
  int ksrc = r * 128 + swsrc;
  int vsrc = r * 4096 + swsrc;

  // read-side XOR bytes
  int swK = (ln & 7) << 4;                              // w(rho) = ln&7
  int swV = ((ln & 3) | (((ln >> 3) & 1) << 2)) << 4;   // w(dt*16+ln)

  f32x4 oacc[2][4];
#pragma unroll
  for (int s = 0; s < 2; ++s)
#pragma unroll
    for (int i = 0; i < 4; ++i) oacc[s][i] = f32x4{0.f, 0.f, 0.f, 0.f};
  f32x4 lacc[2];
  lacc[0] = f32x4{0.f, 0.f, 0.f, 0.f};
  lacc[1] = f32x4{0.f, 0.f, 0.f, 0.f};

  // prologue: stage tile 0 into buf0
  gload16(Kg + ksrc, smem + wave * 1024);
  gload16(Vg + vsrc, smem + 8192 + wave * 1024);
  __syncthreads();

  for (int st = 0; st < 32; ++st) {
    int cb = st & 1;
    if (st < 31) {  // prefetch next tile into the other buffer
      int sb = (st + 1) * 64;
      char* nb = smem + (cb ^ 1) * 16384;
      gload16(Kg + sb * 128 + ksrc, nb + wave * 1024);
      gload16(Vg + sb * 2 + vsrc, nb + 8192 + wave * 1024);
    }
    const char* Kb = smem + cb * 16384;
    const char* Vb = Kb + 8192;

    // S^T = mfma(K,Q) with permuted K rows:
    // sacc[set][t] reg rg = S[q][s = 32(t&1) + 8g + 4(t>>1) + rg]
    f32x4 sacc[2][4];
#pragma unroll
    for (int s = 0; s < 2; ++s)
#pragma unroll
      for (int t = 0; t < 4; ++t) sacc[s][t] = f32x4{0.f, 0.f, 0.f, 0.f};
    __builtin_amdgcn_s_setprio(1);
#pragma unroll
    for (int kt = 0; kt < 2; ++kt) {
      int off = (kt * 64 + g * 16) ^ swK;
#pragma unroll
      for (int t = 0; t < 4; ++t) {
        int rho = 32 * (t & 1) + 8 * (ln >> 2) + 4 * (t >> 1) + (ln & 3);
        s16x8 kf = *reinterpret_cast<const s16x8*>(Kb + rho * 128 + off);
        sacc[0][t] = __builtin_amdgcn_mfma_f32_16x16x32_bf16(kf, qf[0][kt], sacc[0][t], 0, 0, 0);
        sacc[1][t] = __builtin_amdgcn_mfma_f32_16x16x32_bf16(kf, qf[1][kt], sacc[1][t], 0, 0, 0);
      }
    }
    __builtin_amdgcn_s_setprio(0);

    // P = exp2(S) (m fixed 0) -> lane-local PV B-fragments (no LDS)
    s16x8 pf[2][2];
#pragma unroll
    for (int s = 0; s < 2; ++s) {
      float p[4][4];
#pragma unroll
      for (int t = 0; t < 4; ++t)
#pragma unroll
        for (int rg = 0; rg < 4; ++rg)
          p[t][rg] = __builtin_amdgcn_exp2f(sacc[s][t][rg]);
#pragma unroll
      for (int kt = 0; kt < 2; ++kt) {
        u32x4 tw;
        tw[0] = cvtpk(p[kt][0],     p[kt][1]);
        tw[1] = cvtpk(p[kt][2],     p[kt][3]);
        tw[2] = cvtpk(p[kt + 2][0], p[kt + 2][1]);
        tw[3] = cvtpk(p[kt + 2][2], p[kt + 2][3]);
        pf[s][kt] = __builtin_bit_cast(s16x8, tw);
      }
    }

    // l += ones . P  (A=ones: layout-independent row sums into lacc[set][rg])
#pragma unroll
    for (int s = 0; s < 2; ++s)
#pragma unroll
      for (int kt = 0; kt < 2; ++kt)
        lacc[s] = __builtin_amdgcn_mfma_f32_16x16x32_bf16(ones, pf[s][kt], lacc[s], 0, 0, 0);

    // O^T += mfma(V,P): V frag read once, feeds both q-sets
    __builtin_amdgcn_s_setprio(1);
#pragma unroll
    for (int kt = 0; kt < 2; ++kt) {
      int off = (kt * 64 + g * 16) ^ swV;
#pragma unroll
      for (int dt = 0; dt < 4; ++dt) {
        s16x8 vf = *reinterpret_cast<const s16x8*>(Vb + (dt * 16 + ln) * 128 + off);
        oacc[0][dt] = __builtin_amdgcn_mfma_f32_16x16x32_bf16(vf, pf[0][kt], oacc[0][dt], 0, 0, 0);
        oacc[1][dt] = __builtin_amdgcn_mfma_f32_16x16x32_bf16(vf, pf[1][kt], oacc[1][dt], 0, 0, 0);
      }
    }
    __builtin_amdgcn_s_setprio(0);
    __syncthreads();  // drains vmcnt (prefetch) + lgkm; buf swap safe
  }

  // epilogue: y[b, t, h*64 + d] = O[d][q]/l, d = 16dt + 4g + rg
  int b = bh >> 4, h = bh & 15;
#pragma unroll
  for (int s = 0; s < 2; ++s) {
    float linv = 1.0f / lacc[s][0];
    u16* yrow = yb + (b * 2048 + qrow + s * 16) * 1024 + h * 64;
#pragma unroll
    for (int dt = 0; dt < 4; ++dt) {
      uint2 w;
      w.x = cvtpk(oacc[s][dt][0] * linv, oacc[s][dt][1] * linv);
      w.y = cvtpk(oacc[s][dt][2] * linv, oacc[s][dt][3] * linv);
      *reinterpret_cast<uint2*>(yrow + dt * 16 + g * 4) = w;
    }
  }
}

// ---------------------------------------------------------------------------
extern "C" void kernel_launch(void* const* d_in, const int* in_sizes, int n_in,
                              void* d_out, int out_size, void* d_ws, size_t ws_size,
                              hipStream_t stream) {
  (void)in_sizes; (void)n_in; (void)out_size; (void)ws_size;
  const float* x  = (const float*)d_in[0];
  const float* Wq = (const float*)d_in[1];
  const float* bq = (const float*)d_in[2];
  const float* Wk = (const float*)d_in[3];
  const float* bk = (const float*)d_in[4];
  const float* Wv = (const float*)d_in[5];
  const float* bv = (const float*)d_in[6];
  const float* Wp = (const float*)d_in[7];
  const float* bp = (const float*)d_in[8];

  char* ws = (char*)d_ws;
  u16*   xb    = (u16*)(ws);               // 16MB (reused as Y after attention)
  u16*   wbqkv = (u16*)(ws + 16777216);    // 6MB
  u16*   wbp   = (u16*)(ws + 23068672);    // 2MB
  float* alphaf = (float*)(ws + 25165824); // 16KB
  float* biasf  = (float*)(ws + 25182208); // 16KB
  u16*   vtbuf = (u16*)(ws + 25198592);    // 16MB
  u16*   ybuf  = xb;
  u16*   qbuf  = (u16*)d_out;              // d_out (32MB) as Q|K scratch
  u16*   kbuf  = (u16*)d_out + 8388608;
  float* outf  = (float*)d_out;

  k_prep<<<5120, 256, 0, stream>>>(x, xb, Wq, Wk, Wv, Wp, bq, bk, bv, bp, wbqkv, wbp, alphaf, biasf);
  k_gemm<0, 24, 1536, 1><<<1536, 256, 0, stream>>>(xb, wbqkv, alphaf, biasf, qbuf, kbuf, vtbuf, nullptr);
  k_attn<<<512, 512, 0, stream>>>(qbuf, kbuf, vtbuf, ybuf);
  k_gemm<1, 8, 512, 0><<<512, 256, 0, stream>>>(ybuf, wbp, alphaf, biasf, nullptr, nullptr, nullptr, outf);
}